// Round 3
// baseline (26.565 us; speedup 1.0000x reference)
//
#include <hip/hip_runtime.h>

// JPEG differentiable codec, fused. Identity: IDCT(DCT(p)+nf) = p + IDCT(nf);
// only the quantization NOISE is IDCT'd: nf = 0.125*eps*table*AA*rv.
// Round-2: 64x32-px tile / 256 threads / 8 px per thread; fast 8-pt IDCT with
// literal constants in both stages (no cos table, no LDS table reads);
// stage-1 reads rv straight from global; 2 barriers.
//
// Index map (validated rounds 0-1): img[b,i,j,c] = pixel_inp[b,c,j,i];
// Y block n = (i/8)*32 + j/8, in-block (x,y) = (i%8, j%8); ref tables are .T
// so effective table[x][y] = std[y][x]; chroma at (ci,cj)=(i/2,j/2),
// n_c = (ci/8)*16 + cj/8.

__constant__ float YBT[64] = {   // YBT[x*8+y] = std_luma[y][x]
  16,12,14,14,18,24,49,72,
  11,12,13,17,22,35,64,92,
  10,14,16,22,37,55,78,95,
  16,19,24,29,56,64,87,98,
  24,26,40,51,68,81,103,112,
  40,58,57,87,109,104,121,100,
  51,60,69,80,103,113,120,103,
  61,55,56,62,77,92,101,99};

__constant__ float CBTc[64] = {  // symmetric -> transpose = itself
  17,18,24,47,99,99,99,99,
  18,21,26,66,99,99,99,99,
  24,26,56,99,99,99,99,99,
  47,66,99,99,99,99,99,99,
  99,99,99,99,99,99,99,99,
  99,99,99,99,99,99,99,99,
  99,99,99,99,99,99,99,99,
  99,99,99,99,99,99,99,99};

// o[u] = sum_k t[k] * cos((2u+1)*k*pi/16)   (alpha folded upstream)
__device__ __forceinline__ void idct8(const float* __restrict__ t,
                                      float* __restrict__ o) {
    const float r  = 0.70710678118654752f;  // cos(4pi/16)
    const float a  = 0.92387953251128674f;  // cos(2pi/16)
    const float bq = 0.38268343236508977f;  // cos(6pi/16)
    const float c1 = 0.98078528040323044f;
    const float c3 = 0.83146961230254524f;
    const float c5 = 0.55557023301960222f;
    const float c7 = 0.19509032201612827f;
    const float p  = fmaf(r,  t[4], t[0]);
    const float m  = fmaf(-r, t[4], t[0]);
    const float q  = fmaf(a,  t[2],  bq*t[6]);
    const float s  = fmaf(bq, t[2],  -a*t[6]);
    const float E0 = p + q, E3 = p - q, E1 = m + s, E2 = m - s;
    const float O0 = fmaf(c1,t[1], fmaf( c3,t[3], fmaf( c5,t[5],  c7*t[7])));
    const float O1 = fmaf(c3,t[1], fmaf(-c7,t[3], fmaf(-c1,t[5], -c5*t[7])));
    const float O2 = fmaf(c5,t[1], fmaf(-c1,t[3], fmaf( c7,t[5],  c3*t[7])));
    const float O3 = fmaf(c7,t[1], fmaf(-c5,t[3], fmaf( c3,t[5], -c1*t[7])));
    o[0]=E0+O0; o[7]=E0-O0; o[1]=E1+O1; o[6]=E1-O1;
    o[2]=E2+O2; o[5]=E2-O2; o[3]=E3+O3; o[4]=E3-O3;
}

__global__ __launch_bounds__(256) void jpeg_kernel(
    const float* __restrict__ pix,   // [B,3,256,256]
    const float* __restrict__ rvy,   // [B,1024,8,8]
    const float* __restrict__ rvcb,  // [B,256,8,8]
    const float* __restrict__ rvcr,  // [B,256,8,8]
    const float* __restrict__ epsv,  // [B]
    float* __restrict__ out)         // [B,3,256,256]
{
    __shared__ float sY[32*72];      // stage-1 Y out: [n][v][x^swz], n-stride 72
    __shared__ float sC[16*72];      // chroma (8 Cb + 8 Cr blocks)
    __shared__ float pool[2*576];    // pooled chroma (centered): [ch][cj][ci], cj-stride 36

    const int tid = threadIdx.x;
    const int b   = blockIdx.y;
    const int ti  = blockIdx.x >> 3;   // 64-px tile in i
    const int tj  = blockIdx.x & 7;    // 32-px tile in j
    const int qi  = tid & 7;           // i-octet
    const int dj  = tid >> 3;          // row 0..31

    const float eps8 = epsv[b] * 0.125f;   // 0.25(idct)*0.5(noisy_round)
    const float RT   = 0.70710678118654752f;

    // ---------- phase 1a: pixel loads + YCC + chroma pool ----------
    const int i0 = ti*64 + qi*8;
    const int j  = tj*32 + dj;
    const size_t pb = (size_t)b*196608 + (size_t)j*256 + i0;
    const float4 rA = *(const float4*)(pix + pb);
    const float4 rB = *(const float4*)(pix + pb + 4);
    const float4 gA = *(const float4*)(pix + pb + 65536);
    const float4 gB = *(const float4*)(pix + pb + 65540);
    const float4 bA = *(const float4*)(pix + pb + 131072);
    const float4 bB = *(const float4*)(pix + pb + 131076);

    float rr[8] = {rA.x,rA.y,rA.z,rA.w,rB.x,rB.y,rB.z,rB.w};
    float gg[8] = {gA.x,gA.y,gA.z,gA.w,gB.x,gB.y,gB.z,gB.w};
    float bb[8] = {bA.x,bA.y,bA.z,bA.w,bB.x,bB.y,bB.z,bB.w};
    float yv[8], cbv[8], crv[8];
    #pragma unroll
    for (int c = 0; c < 8; ++c) {
        yv[c]  = fmaf(0.299f, rr[c], fmaf(0.587f, gg[c], 0.114f*bb[c]));
        cbv[c] = fmaf(-0.168736f, rr[c], fmaf(-0.331264f, gg[c], 0.5f*bb[c]));
        crv[c] = fmaf(0.5f, rr[c], fmaf(-0.418688f, gg[c], -0.081312f*bb[c]));
    }
    float cbs[4], crs[4];
    #pragma unroll
    for (int k = 0; k < 4; ++k) {
        cbs[k] = cbv[2*k] + cbv[2*k+1];
        crs[k] = crv[2*k] + crv[2*k+1];
        cbs[k] += __shfl_xor(cbs[k], 8);   // partner row j^1
        crs[k] += __shfl_xor(crs[k], 8);
    }
    if ((dj & 1) == 0) {   // centered pooled chroma (no +128)
        const int cj = dj >> 1;
        float* pp = &pool[cj*36 + qi*4];
        *(float4*)pp        = make_float4(0.25f*cbs[0],0.25f*cbs[1],0.25f*cbs[2],0.25f*cbs[3]);
        *(float4*)(pp+576)  = make_float4(0.25f*crs[0],0.25f*crs[1],0.25f*crs[2],0.25f*crs[3]);
    }

    // ---------- phase 1b: stage-1 Y (one column IDCT per thread) ----------
    {
        const int nl = tid >> 3;          // local Y block 0..31
        const int xc = tid & 7;           // column x
        const int bx = nl >> 2, by = nl & 3;
        const size_t ng = (size_t)((ti*8 + bx)*32 + tj*4 + by);
        const float* rp = rvy + ((size_t)b*1024 + ng)*64 + xc*8;
        const float4 v0 = *(const float4*)rp;
        const float4 v1 = *(const float4*)(rp + 4);
        const float4 y0 = *(const float4*)&YBT[xc*8];
        const float4 y1 = *(const float4*)&YBT[xc*8 + 4];
        const float aax = (xc == 0 ? RT : 1.0f) * eps8;
        float t[8];
        t[0] = v0.x * (y0.x * aax * RT);  // alpha_y on y=0
        t[1] = v0.y * (y0.y * aax);
        t[2] = v0.z * (y0.z * aax);
        t[3] = v0.w * (y0.w * aax);
        t[4] = v1.x * (y1.x * aax);
        t[5] = v1.y * (y1.y * aax);
        t[6] = v1.z * (y1.z * aax);
        t[7] = v1.w * (y1.w * aax);
        float o[8];
        idct8(t, o);
        const int swz = (bx & 1) * 4;     // (nl>>2)&1
        float* wY = &sY[nl*72 + (xc ^ swz)];
        #pragma unroll
        for (int v = 0; v < 8; ++v) wY[v*8] = o[v];
    }
    // ---------- phase 1c: stage-1 chroma (tid<128) ----------
    if (tid < 128) {
        const int nc = tid >> 3;          // 0..15 (ch = nc>>3)
        const int xc = tid & 7;
        const int ch = nc >> 3, idx = nc & 7, cbx = idx >> 1, cby = idx & 1;
        const size_t ng = (size_t)((ti*4 + cbx)*16 + tj*2 + cby);
        const float* __restrict__ rvc = ch ? rvcr : rvcb;
        const float* rp = rvc + ((size_t)b*256 + ng)*64 + xc*8;
        const float4 v0 = *(const float4*)rp;
        const float4 v1 = *(const float4*)(rp + 4);
        const float4 y0 = *(const float4*)&CBTc[xc*8];
        const float4 y1 = *(const float4*)&CBTc[xc*8 + 4];
        const float aax = (xc == 0 ? RT : 1.0f) * eps8;
        float t[8];
        t[0] = v0.x * (y0.x * aax * RT);
        t[1] = v0.y * (y0.y * aax);
        t[2] = v0.z * (y0.z * aax);
        t[3] = v0.w * (y0.w * aax);
        t[4] = v1.x * (y1.x * aax);
        t[5] = v1.y * (y1.y * aax);
        t[6] = v1.z * (y1.z * aax);
        t[7] = v1.w * (y1.w * aax);
        float o[8];
        idct8(t, o);
        const int swz = ((nc >> 2) & 1) * 4;
        float* wC = &sC[nc*72 + (xc ^ swz)];
        #pragma unroll
        for (int v = 0; v < 8; ++v) wC[v*8] = o[v];
    }
    __syncthreads();   // A: sY/sC/pool ready

    // ---------- phase 2a: stage-2 Y (full u-row per thread, in regs) ----------
    float yn[8];
    {
        const int n2 = qi*4 + (dj >> 3);
        const int v2 = dj & 7;
        const int s2 = (qi & 1) * 4;      // (n2>>2)&1
        const float* rY = &sY[n2*72 + v2*8];
        const float4 lo = *(const float4*)(rY + s2);
        const float4 hi = *(const float4*)(rY + (s2 ^ 4));
        float t[8] = {lo.x,lo.y,lo.z,lo.w,hi.x,hi.y,hi.z,hi.w};
        idct8(t, yn);
    }
    // ---------- phase 2b: stage-2 chroma + combine into pool (tid<128) ----------
    if (tid < 128) {
        const int nc2 = tid >> 3;
        const int vc2 = tid & 7;
        const int sc2 = ((nc2 >> 2) & 1) * 4;
        const float* rC = &sC[nc2*72 + vc2*8];
        const float4 lo = *(const float4*)(rC + sc2);
        const float4 hi = *(const float4*)(rC + (sc2 ^ 4));
        float t[8] = {lo.x,lo.y,lo.z,lo.w,hi.x,hi.y,hi.z,hi.w};
        float cn[8];
        idct8(t, cn);
        const int ch = nc2 >> 3, idx = nc2 & 7, cbx = idx >> 1, cby = idx & 1;
        const int cj = cby*8 + vc2;
        float* pp = &pool[ch*576 + cj*36 + cbx*8];
        const float4 p0 = *(const float4*)pp;
        const float4 p1 = *(const float4*)(pp + 4);
        *(float4*)pp       = make_float4(p0.x+cn[0], p0.y+cn[1], p0.z+cn[2], p0.w+cn[3]);
        *(float4*)(pp + 4) = make_float4(p1.x+cn[4], p1.y+cn[5], p1.z+cn[6], p1.w+cn[7]);
    }
    __syncthreads();   // B: chroma-final ready

    // ---------- phase 3: recombine, YCC->RGB, clip, store ----------
    const int cjf = dj >> 1;
    const float4 cb4 = *(const float4*)&pool[cjf*36 + qi*4];
    const float4 cr4 = *(const float4*)&pool[576 + cjf*36 + qi*4];
    const float cbf[8] = {cb4.x,cb4.x,cb4.y,cb4.y,cb4.z,cb4.z,cb4.w,cb4.w};
    const float crf[8] = {cr4.x,cr4.x,cr4.y,cr4.y,cr4.z,cr4.z,cr4.w,cr4.w};
    float ro[8], go[8], bo[8];
    #pragma unroll
    for (int c = 0; c < 8; ++c) {
        const float yf = yv[c] + yn[c];
        float r_ = fmaf(1.402f, crf[c], yf);
        float g_ = fmaf(-0.344136f, cbf[c], fmaf(-0.714136f, crf[c], yf));
        float b_ = fmaf(1.772f, cbf[c], yf);
        ro[c] = fminf(fmaxf(r_, 0.0f), 255.0f);
        go[c] = fminf(fmaxf(g_, 0.0f), 255.0f);
        bo[c] = fminf(fmaxf(b_, 0.0f), 255.0f);
    }
    *(float4*)(out + pb)          = make_float4(ro[0],ro[1],ro[2],ro[3]);
    *(float4*)(out + pb + 4)      = make_float4(ro[4],ro[5],ro[6],ro[7]);
    *(float4*)(out + pb + 65536)  = make_float4(go[0],go[1],go[2],go[3]);
    *(float4*)(out + pb + 65540)  = make_float4(go[4],go[5],go[6],go[7]);
    *(float4*)(out + pb + 131072) = make_float4(bo[0],bo[1],bo[2],bo[3]);
    *(float4*)(out + pb + 131076) = make_float4(bo[4],bo[5],bo[6],bo[7]);
}

extern "C" void kernel_launch(void* const* d_in, const int* in_sizes, int n_in,
                              void* d_out, int out_size, void* d_ws, size_t ws_size,
                              hipStream_t stream) {
    const float* pix  = (const float*)d_in[0];
    const float* rvy  = (const float*)d_in[1];
    const float* rvcb = (const float*)d_in[2];
    const float* rvcr = (const float*)d_in[3];
    const float* eps  = (const float*)d_in[4];
    const int B = in_sizes[4];           // epsilon: one per batch
    dim3 grid(32, B);                    // 4x8 tiles of 64x32 px, per batch
    jpeg_kernel<<<grid, 256, 0, stream>>>(pix, rvy, rvcb, rvcr, eps, (float*)d_out);
}

// Round 4
// 24.617 us; speedup vs baseline: 1.0791x; 1.0791x over previous
//
#include <hip/hip_runtime.h>

// JPEG differentiable codec, fused. Identity: IDCT(DCT(p)+nf) = p + IDCT(nf);
// only the quantization NOISE is IDCT'd: nf = 0.125*eps*table*AA*rv.
// Round-3: 32x32-px tile / 256 threads / 4 px per thread (low VGPR), fast
// 8-pt IDCT butterflies (literal constants) in both stages, rv read straight
// from global, loads ordered rv->tables->pixels so stage-1 overlaps pixel
// latency. Wave-aligned stage split: waves 0-1 Y, wave 2 chroma. 2 barriers.
// LDS banks re-derived with per-octet model: stride-68 stage buffers,
// stride-36 nylds, stride-20 pool -> all accesses <=2-way.
//
// Index map (validated rounds 0-2): img[b,i,j,c] = pixel_inp[b,c,j,i];
// Y block n = (i/8)*32 + j/8, in-block (x,y) = (i%8, j%8); ref tables are .T
// so effective table[x][y] = std[y][x]; chroma at (ci,cj)=(i/2,j/2),
// n_c = (ci/8)*16 + cj/8.

__constant__ float YBT[64] = {   // YBT[x*8+y] = std_luma[y][x]
  16,12,14,14,18,24,49,72,
  11,12,13,17,22,35,64,92,
  10,14,16,22,37,55,78,95,
  16,19,24,29,56,64,87,98,
  24,26,40,51,68,81,103,112,
  40,58,57,87,109,104,121,100,
  51,60,69,80,103,113,120,103,
  61,55,56,62,77,92,101,99};

__constant__ float CBTc[64] = {  // symmetric -> transpose = itself
  17,18,24,47,99,99,99,99,
  18,21,26,66,99,99,99,99,
  24,26,56,99,99,99,99,99,
  47,66,99,99,99,99,99,99,
  99,99,99,99,99,99,99,99,
  99,99,99,99,99,99,99,99,
  99,99,99,99,99,99,99,99,
  99,99,99,99,99,99,99,99};

// o[u] = sum_k t[k] * cos((2u+1)*k*pi/16)   (alpha folded upstream)
__device__ __forceinline__ void idct8(const float* __restrict__ t,
                                      float* __restrict__ o) {
    const float r  = 0.70710678118654752f;  // cos(4pi/16)
    const float a  = 0.92387953251128674f;  // cos(2pi/16)
    const float bq = 0.38268343236508977f;  // cos(6pi/16)
    const float c1 = 0.98078528040323044f;
    const float c3 = 0.83146961230254524f;
    const float c5 = 0.55557023301960222f;
    const float c7 = 0.19509032201612827f;
    const float p  = fmaf(r,  t[4], t[0]);
    const float m  = fmaf(-r, t[4], t[0]);
    const float q  = fmaf(a,  t[2],  bq*t[6]);
    const float s  = fmaf(bq, t[2],  -a*t[6]);
    const float E0 = p + q, E3 = p - q, E1 = m + s, E2 = m - s;
    const float O0 = fmaf(c1,t[1], fmaf( c3,t[3], fmaf( c5,t[5],  c7*t[7])));
    const float O1 = fmaf(c3,t[1], fmaf(-c7,t[3], fmaf(-c1,t[5], -c5*t[7])));
    const float O2 = fmaf(c5,t[1], fmaf(-c1,t[3], fmaf( c7,t[5],  c3*t[7])));
    const float O3 = fmaf(c7,t[1], fmaf(-c5,t[3], fmaf( c3,t[5], -c1*t[7])));
    o[0]=E0+O0; o[7]=E0-O0; o[1]=E1+O1; o[6]=E1-O1;
    o[2]=E2+O2; o[5]=E2-O2; o[3]=E3+O3; o[4]=E3-O3;
}

__global__ __launch_bounds__(256) void jpeg_kernel(
    const float* __restrict__ pix,   // [B,3,256,256]
    const float* __restrict__ rvy,   // [B,1024,8,8]
    const float* __restrict__ rvcb,  // [B,256,8,8]
    const float* __restrict__ rvcr,  // [B,256,8,8]
    const float* __restrict__ epsv,  // [B]
    float* __restrict__ out)         // [B,3,256,256]
{
    __shared__ float sY[16*68];      // stage-1 Y: [nl][x][v], block stride 68
    __shared__ float sC[8*68];       // 4 Cb + 4 Cr
    __shared__ float nylds[32*36];   // Y noise [j][i], row stride 36
    __shared__ float pool[2*320];    // centered pooled chroma [ch][cj][ci], cj stride 20

    const int tid = threadIdx.x;
    const int qi  = tid & 7;           // i-quad (4 px)
    const int dj  = tid >> 3;          // row 0..31
    const int b   = blockIdx.y;
    const int ti  = blockIdx.x >> 3;   // 32-px tile in i
    const int tj  = blockIdx.x & 7;    // 32-px tile in j

    const float eps8 = epsv[b] * 0.125f;   // 0.25(idct)*0.5(noisy_round)
    const float RT   = 0.70710678118654752f;

    // ---- issue stage-1 loads FIRST (rv + table), pixels second, so the
    //      stage-1 idct only waits on the early vmem ops ----
    float4 v0, v1, t0, t1;
    int nl = 0;
    const int xc = tid & 7;
    const bool isY = tid < 128, isC = (tid >= 128) && (tid < 192);
    if (isY) {
        nl = tid >> 3;                               // 0..15
        const int bx = nl >> 2, by = nl & 3;
        const int ng = (ti*4 + bx)*32 + (tj*4 + by);
        const float* rp = rvy + ((size_t)b*1024 + ng)*64 + xc*8;
        v0 = *(const float4*)rp;
        v1 = *(const float4*)(rp + 4);
        t0 = *(const float4*)&YBT[xc*8];
        t1 = *(const float4*)&YBT[xc*8 + 4];
    } else if (isC) {
        nl = (tid - 128) >> 3;                       // 0..7; ch = nl>>2
        const int ch = nl >> 2, idx = nl & 3, cbx = idx >> 1, cby = idx & 1;
        const int ng = (ti*2 + cbx)*16 + (tj*2 + cby);
        const float* __restrict__ rvc = ch ? rvcr : rvcb;
        const float* rp = rvc + ((size_t)b*256 + ng)*64 + xc*8;
        v0 = *(const float4*)rp;
        v1 = *(const float4*)(rp + 4);
        t0 = *(const float4*)&CBTc[xc*8];
        t1 = *(const float4*)&CBTc[xc*8 + 4];
    }

    const int i0 = ti*32 + qi*4;
    const int j  = tj*32 + dj;
    const size_t pb = (size_t)b*196608 + (size_t)j*256 + i0;
    const float4 rP = *(const float4*)(pix + pb);
    const float4 gP = *(const float4*)(pix + pb + 65536);
    const float4 bP = *(const float4*)(pix + pb + 131072);

    // ---- stage 1: column IDCT of scaled noise (waves 0-2) ----
    if (isY || isC) {
        const float aax = (xc == 0 ? RT : 1.0f) * eps8;
        float t[8];
        t[0] = v0.x * (t0.x * aax * RT);   // alpha_y on y=0
        t[1] = v0.y * (t0.y * aax);
        t[2] = v0.z * (t0.z * aax);
        t[3] = v0.w * (t0.w * aax);
        t[4] = v1.x * (t1.x * aax);
        t[5] = v1.y * (t1.y * aax);
        t[6] = v1.z * (t1.z * aax);
        t[7] = v1.w * (t1.w * aax);
        float o[8];
        idct8(t, o);
        float* ws = (isY ? sY : sC) + nl*68 + xc*8;
        *(float4*)ws       = make_float4(o[0], o[1], o[2], o[3]);
        *(float4*)(ws + 4) = make_float4(o[4], o[5], o[6], o[7]);
    }

    // ---- YCC + chroma 2x2 pool (all threads; pixels have arrived) ----
    const float rr[4] = {rP.x, rP.y, rP.z, rP.w};
    const float gg[4] = {gP.x, gP.y, gP.z, gP.w};
    const float bb[4] = {bP.x, bP.y, bP.z, bP.w};
    float yv[4], cbv[4], crv[4];
    #pragma unroll
    for (int c = 0; c < 4; ++c) {
        yv[c]  = fmaf(0.299f, rr[c], fmaf(0.587f, gg[c], 0.114f*bb[c]));
        cbv[c] = fmaf(-0.168736f, rr[c], fmaf(-0.331264f, gg[c], 0.5f*bb[c]));
        crv[c] = fmaf(0.5f, rr[c], fmaf(-0.418688f, gg[c], -0.081312f*bb[c]));
    }
    float cb01 = cbv[0] + cbv[1], cb23 = cbv[2] + cbv[3];
    float cr01 = crv[0] + crv[1], cr23 = crv[2] + crv[3];
    cb01 += __shfl_xor(cb01, 8);   // partner row j^1 (dj bit0 = lane bit3)
    cb23 += __shfl_xor(cb23, 8);
    cr01 += __shfl_xor(cr01, 8);
    cr23 += __shfl_xor(cr23, 8);
    if ((dj & 1) == 0) {           // centered pooled chroma (no +128)
        float* pp = &pool[(dj >> 1)*20 + qi*2];
        *(float2*)pp         = make_float2(0.25f*cb01, 0.25f*cb23);
        *(float2*)(pp + 320) = make_float2(0.25f*cr01, 0.25f*cr23);
    }
    __syncthreads();   // A: sY/sC/pool ready

    // ---- stage 2: row IDCT ----
    if (tid < 128) {               // Y rows -> nylds
        const int n2 = tid >> 3, v2 = tid & 7;
        const float* rs = &sY[n2*68 + v2];
        float t[8];
        #pragma unroll
        for (int x = 0; x < 8; ++x) t[x] = rs[x*8];
        float o[8];
        idct8(t, o);
        const int jj = (n2 & 3)*8 + v2;
        float* wn = &nylds[jj*36 + (n2 >> 2)*8];
        *(float4*)wn       = make_float4(o[0], o[1], o[2], o[3]);
        *(float4*)(wn + 4) = make_float4(o[4], o[5], o[6], o[7]);
    } else if (tid < 192) {        // chroma rows -> add into pool
        const int c2 = tid - 128;
        const int nc2 = c2 >> 3, vc2 = c2 & 7;
        const float* rs = &sC[nc2*68 + vc2];
        float t[8];
        #pragma unroll
        for (int x = 0; x < 8; ++x) t[x] = rs[x*8];
        float o[8];
        idct8(t, o);
        const int ch = nc2 >> 2, idx = nc2 & 3, cbx = idx >> 1, cby = idx & 1;
        float* pp = &pool[ch*320 + (cby*8 + vc2)*20 + cbx*8];
        const float4 p0 = *(const float4*)pp;
        const float4 p1 = *(const float4*)(pp + 4);
        *(float4*)pp       = make_float4(p0.x+o[0], p0.y+o[1], p0.z+o[2], p0.w+o[3]);
        *(float4*)(pp + 4) = make_float4(p1.x+o[4], p1.y+o[5], p1.z+o[6], p1.w+o[7]);
    }
    __syncthreads();   // B: nylds + chroma-final pool ready

    // ---- final: recombine, YCC->RGB, clip, store ----
    const float4 yn4 = *(const float4*)&nylds[dj*36 + qi*4];
    const int cj = dj >> 1;
    const float2 cbp = *(const float2*)&pool[cj*20 + qi*2];
    const float2 crp = *(const float2*)&pool[320 + cj*20 + qi*2];
    const float yn[4]  = {yn4.x, yn4.y, yn4.z, yn4.w};
    const float cbf[4] = {cbp.x, cbp.x, cbp.y, cbp.y};
    const float crf[4] = {crp.x, crp.x, crp.y, crp.y};
    float ro[4], go[4], bo[4];
    #pragma unroll
    for (int c = 0; c < 4; ++c) {
        const float yf = yv[c] + yn[c];
        float r_ = fmaf(1.402f, crf[c], yf);
        float g_ = fmaf(-0.344136f, cbf[c], fmaf(-0.714136f, crf[c], yf));
        float b_ = fmaf(1.772f, cbf[c], yf);
        ro[c] = fminf(fmaxf(r_, 0.0f), 255.0f);
        go[c] = fminf(fmaxf(g_, 0.0f), 255.0f);
        bo[c] = fminf(fmaxf(b_, 0.0f), 255.0f);
    }
    *(float4*)(out + pb)          = make_float4(ro[0], ro[1], ro[2], ro[3]);
    *(float4*)(out + pb + 65536)  = make_float4(go[0], go[1], go[2], go[3]);
    *(float4*)(out + pb + 131072) = make_float4(bo[0], bo[1], bo[2], bo[3]);
}

extern "C" void kernel_launch(void* const* d_in, const int* in_sizes, int n_in,
                              void* d_out, int out_size, void* d_ws, size_t ws_size,
                              hipStream_t stream) {
    const float* pix  = (const float*)d_in[0];
    const float* rvy  = (const float*)d_in[1];
    const float* rvcb = (const float*)d_in[2];
    const float* rvcr = (const float*)d_in[3];
    const float* eps  = (const float*)d_in[4];
    const int B = in_sizes[4];           // epsilon: one per batch
    dim3 grid(64, B);                    // 8x8 tiles of 32x32 px, per batch
    jpeg_kernel<<<grid, 256, 0, stream>>>(pix, rvy, rvcb, rvcr, eps, (float*)d_out);
}